// Round 9
// baseline (238.303 us; speedup 1.0000x reference)
//
#include <hip/hip_runtime.h>
#include <math.h>
#include <float.h>

#define BS 256
#define MAXC 31
#define MAXGT (BS * MAXC)   // 7936 max gt rows per block
typedef unsigned long long u64;
typedef unsigned char u8;

// ws layout (nb = 1024):
//   [0, 4K)        int blockOffsets[nb]
//   [4K, 4K+4)     int done
//   [8K, 24K)      float4 partials[nb]

// One block, 1024 threads: chunk sums (wave-cooperative, coalesced) + scan.
__global__ void __launch_bounds__(1024)
scan_kernel(const int* __restrict__ counts, int* __restrict__ blockOffsets,
            int* __restrict__ done, int N, int nb) {
    __shared__ int cs[1024];
    __shared__ int wt[16];
    const int t = threadIdx.x, lane = t & 63, w = t >> 6;  // 16 waves
    // wave w computes sums of chunks [w*64, w*64+64), each chunk = 256 ints
    for (int k = 0; k < 64; ++k) {
        const int c = w * 64 + k;
        int s = 0;
#pragma unroll
        for (int q = 0; q < 4; ++q) {
            const int idx = c * BS + q * 64 + lane;  // wave-coalesced
            s += (idx < N) ? counts[idx] : 0;
        }
        for (int o = 32; o > 0; o >>= 1) s += __shfl_down(s, o, 64);
        if (lane == 0) cs[c] = s;
    }
    if (t == 0) *done = 0;
    __syncthreads();
    // exclusive scan of cs[1024]
    const int v = (t < nb) ? cs[t] : 0;
    int incl = v;
    for (int o = 1; o < 64; o <<= 1) {
        int x = __shfl_up(incl, o, 64);
        if (lane >= o) incl += x;
    }
    if (lane == 63) wt[w] = incl;
    __syncthreads();
    if (w == 0 && lane < 16) {
        const int x = wt[lane];
        int wi = x;
        for (int o = 1; o < 16; o <<= 1) {
            int y = __shfl_up(wi, o, 64);
            if (lane >= o) wi += y;
        }
        wt[lane] = wi - x;
    }
    __syncthreads();
    if (t < nb) blockOffsets[t] = wt[w] + incl - v;
}

// Block b owns pred rows [b*256, b*256+256) and their contiguous gt range.
// ownerMap (u8) = O(1) segment lookup; guarded LDS u64 atomicMin = exact
// (min d2, lowest row). Finalize folded in via done-counter: partials stored
// with atomicExch (device-scope visible), last block reads via atomicAdd+0.
__global__ void __launch_bounds__(BS)
fused_kernel(const float* __restrict__ pred, const float* __restrict__ gt,
             const int* __restrict__ counts, const int* __restrict__ blockOffsets,
             float* __restrict__ partials, int* __restrict__ done,
             float* __restrict__ out, int N, int nb) {
    const int t = threadIdx.x;
    const int b = blockIdx.x;
    const int i = b * BS + t;
    const int lane = t & 63, w = t >> 6;

    __shared__ u8 ownerMap[MAXGT];      // 7936 B
    __shared__ float2 pxy[BS];          // 2048 B
    __shared__ u64 bestLds[BS];         // 2048 B
    __shared__ int waveTot[BS / 64];
    __shared__ int sTotal;
    __shared__ float red[BS / 64][4];
    __shared__ int lastFlag;

    const int c = (i < N) ? counts[i] : 0;
    int incl = c;
    for (int o = 1; o < 64; o <<= 1) {
        int x = __shfl_up(incl, o, 64);
        if (lane >= o) incl += x;
    }
    if (lane == 63) waveTot[w] = incl;
    __syncthreads();
    int wbase = 0;
    for (int ww = 0; ww < w; ++ww) wbase += waveTot[ww];
    const int localStart = wbase + incl - c;
    if (t == BS - 1) sTotal = localStart + c;
    bestLds[t] = ~0ULL;
    if (i < N) pxy[t] = reinterpret_cast<const float2*>(pred)[(size_t)i * 3];
    for (int j = 0; j < c; ++j) ownerMap[localStart + j] = (u8)t;
    __syncthreads();

    const int base = blockOffsets[b];
    const int blockTotal = sTotal;
    const float2* gxy = reinterpret_cast<const float2*>(gt);

    for (int tile = 0; tile < blockTotal; tile += BS * 4) {
        int j[4]; float2 g[4]; bool valid[4];
#pragma unroll
        for (int u = 0; u < 4; ++u) {
            j[u] = tile + u * BS + t;
            valid[u] = j[u] < blockTotal;
            if (valid[u]) g[u] = gxy[(size_t)(base + j[u]) * 3];
        }
#pragma unroll
        for (int u = 0; u < 4; ++u) {
            if (valid[u]) {
                const int owner = (int)ownerMap[j[u]];
                const float2 p = pxy[owner];
                const float dx = p.x - g[u].x, dy = p.y - g[u].y;
                const float d2 = dx * dx + dy * dy;  // >=0: IEEE-monotone bits
                const u64 key = ((u64)__float_as_uint(d2) << 32)
                              | (unsigned int)(base + j[u]);
                if (key < bestLds[owner]) atomicMin(&bestLds[owner], key);
            }
        }
    }
    __syncthreads();

    float lp = 0.f, la = 0.f, lw = 0.f, ls = 0.f;
    if (i < N && c > 0) {
        const u64 key = bestLds[t];
        const float d2 = __uint_as_float((unsigned int)(key >> 32));
        const int bj = (int)(key & 0xffffffffu);
        lp = 1.0f - expf(-d2 / 0.045f);  // max resp == exp(-min d2/(2 sigma^2))

        const float* p = pred + (size_t)i * 6;
        const float2 p23 = *reinterpret_cast<const float2*>(p + 2);
        const float2 p45 = *reinterpret_cast<const float2*>(p + 4);
        const float* ng = gt + (size_t)bj * 6;
        const float2 g23 = *reinterpret_cast<const float2*>(ng + 2);
        const float2 g45 = *reinterpret_cast<const float2*>(ng + 4);

        la = fabsf(p23.x - g23.x) + fabsf(p23.y - g23.y);
        const float d = p45.x - g45.x;
        const float ad = fabsf(d);
        lw = (ad < 1.0f) ? 0.5f * d * d : ad - 0.5f;
        const float x = p45.y;
        if (g45.y > 0.0f) {
            ls = fmaxf(x, 0.0f) - x * g45.y + log1pf(expf(-fabsf(x)));
        }
    }

    for (int o = 32; o > 0; o >>= 1) {
        lp += __shfl_down(lp, o, 64);
        la += __shfl_down(la, o, 64);
        lw += __shfl_down(lw, o, 64);
        ls += __shfl_down(ls, o, 64);
    }
    if (lane == 0) { red[w][0] = lp; red[w][1] = la; red[w][2] = lw; red[w][3] = ls; }
    __syncthreads();
    if (t == 0) {
        float s0 = 0, s1 = 0, s2 = 0, s3 = 0;
        for (int ww = 0; ww < BS / 64; ++ww) {
            s0 += red[ww][0]; s1 += red[ww][1]; s2 += red[ww][2]; s3 += red[ww][3];
        }
        // device-scope-visible stores to distinct slots (no contention)
        atomicExch(&partials[b * 4 + 0], s0);
        atomicExch(&partials[b * 4 + 1], s1);
        atomicExch(&partials[b * 4 + 2], s2);
        atomicExch(&partials[b * 4 + 3], s3);
        __threadfence();
        const int prev = atomicAdd(done, 1);
        lastFlag = (prev == nb - 1) ? 1 : 0;
    }
    __syncthreads();
    if (lastFlag) {
        __threadfence();
        // 256 threads read nb*4 floats via coherent atomic reads
        double s0 = 0, s1 = 0, s2 = 0, s3 = 0;
        for (int q = t; q < nb; q += BS) {
            s0 += (double)atomicAdd(&partials[q * 4 + 0], 0.0f);
            s1 += (double)atomicAdd(&partials[q * 4 + 1], 0.0f);
            s2 += (double)atomicAdd(&partials[q * 4 + 2], 0.0f);
            s3 += (double)atomicAdd(&partials[q * 4 + 3], 0.0f);
        }
        for (int o = 32; o > 0; o >>= 1) {
            s0 += __shfl_down(s0, o, 64);
            s1 += __shfl_down(s1, o, 64);
            s2 += __shfl_down(s2, o, 64);
            s3 += __shfl_down(s3, o, 64);
        }
        __shared__ double dred[BS / 64][4];
        if (lane == 0) { dred[w][0] = s0; dred[w][1] = s1; dred[w][2] = s2; dred[w][3] = s3; }
        __syncthreads();
        if (t == 0) {
            double t0 = 0, t1 = 0, t2 = 0, t3 = 0;
            for (int ww = 0; ww < BS / 64; ++ww) {
                t0 += dred[ww][0]; t1 += dred[ww][1]; t2 += dred[ww][2]; t3 += dred[ww][3];
            }
            const double inv = 1.0 / (double)N;
            const float flp = (float)(t0 * inv);
            const float fla = (float)(t1 * inv);
            const float flw = (float)(t2 * inv);
            const float fls = (float)(t3 * inv);
            out[0] = flp; out[1] = fla; out[2] = flw; out[3] = fls;
            out[4] = flp + fla + flw + 0.5f * fls;
        }
    }
}

extern "C" void kernel_launch(void* const* d_in, const int* in_sizes, int n_in,
                              void* d_out, int out_size, void* d_ws, size_t ws_size,
                              hipStream_t stream) {
    const float* pred = (const float*)d_in[0];
    const float* gt = (const float*)d_in[1];
    const int* counts = (const int*)d_in[2];
    float* out = (float*)d_out;

    const int N = in_sizes[2];
    const int nb = (N + BS - 1) / BS;  // 1024

    int* blockOffsets = (int*)d_ws;
    int* done = (int*)((char*)d_ws + 4096);
    float* partials = (float*)((char*)d_ws + 8192);

    scan_kernel<<<1, 1024, 0, stream>>>(counts, blockOffsets, done, N, nb);
    fused_kernel<<<nb, BS, 0, stream>>>(pred, gt, counts, blockOffsets,
                                        partials, done, out, N, nb);
}

// Round 10
// 172.059 us; speedup vs baseline: 1.3850x; 1.3850x over previous
//
#include <hip/hip_runtime.h>
#include <math.h>
#include <float.h>

#define ROWS 128            // pred rows per fused block
#define TPB 256             // threads per fused block
#define MAXC 31
#define MAXGT (ROWS * MAXC) // 3968
typedef unsigned long long u64;
typedef unsigned char u8;

// ws layout (nb = 2048):
//   [0, 8K)        int blockSums[nb]
//   [8K, 16K)      int blockOffsets[nb]
//   [16K, 48K)     float4 partials[nb]

// 2048 blocks x 64 threads; each sums 128 counts (2 coalesced reads/lane).
__global__ void block_sum_kernel(const int* __restrict__ counts,
                                 int* __restrict__ blockSums, int N) {
    const int base = blockIdx.x * ROWS;
    const int i0 = base + threadIdx.x, i1 = base + 64 + threadIdx.x;
    int v = ((i0 < N) ? counts[i0] : 0) + ((i1 < N) ? counts[i1] : 0);
    for (int o = 32; o > 0; o >>= 1) v += __shfl_down(v, o, 64);
    if (threadIdx.x == 0) blockSums[blockIdx.x] = v;
}

// Exclusive scan of 2048 sums: 1024 threads x 2 elems, shfl-based.
__global__ void scan_kernel(const int* __restrict__ blockSums,
                            int* __restrict__ blockOffsets, int nb) {
    const int t = threadIdx.x, lane = t & 63, w = t >> 6;  // 16 waves
    __shared__ int wt[16];
    const int e0 = 2 * t, e1 = 2 * t + 1;
    const int v0 = (e0 < nb) ? blockSums[e0] : 0;
    const int v1 = (e1 < nb) ? blockSums[e1] : 0;
    const int s = v0 + v1;
    int incl = s;
    for (int o = 1; o < 64; o <<= 1) {
        int x = __shfl_up(incl, o, 64);
        if (lane >= o) incl += x;
    }
    if (lane == 63) wt[w] = incl;
    __syncthreads();
    if (w == 0 && lane < 16) {
        const int x = wt[lane];
        int wi = x;
        for (int o = 1; o < 16; o <<= 1) {
            int y = __shfl_up(wi, o, 64);
            if (lane >= o) wi += y;
        }
        wt[lane] = wi - x;
    }
    __syncthreads();
    const int excl = wt[w] + incl - s;
    if (e0 < nb) blockOffsets[e0] = excl;
    if (e1 < nb) blockOffsets[e1] = excl + v0;
}

// Block b owns pred rows [b*128, b*128+128) and their contiguous gt range
// (<= 3968 rows). 2048 blocks -> 8 blocks/CU -> 32 waves/CU (100% occ).
// Gather loop: barrier-free, 8-deep unrolled -> 8 wave-loads in flight.
__global__ void __launch_bounds__(TPB)
fused_kernel(const float* __restrict__ pred, const float* __restrict__ gt,
             const int* __restrict__ counts, const int* __restrict__ blockOffsets,
             float4* __restrict__ partials, int N) {
    const int t = threadIdx.x;
    const int b = blockIdx.x;
    const int lane = t & 63, w = t >> 6;

    __shared__ u8 ownerMap[MAXGT];     // 3968 B
    __shared__ float predS[ROWS * 6];  // 3072 B (dense pred tile)
    __shared__ u64 bestLds[ROWS];      // 1024 B
    __shared__ int waveTot[TPB / 64];
    __shared__ int sTotal;
    __shared__ float red[TPB / 64][4];

    // dense pred staging: 192 float4 = 128 rows x 6 floats
    if (t < ROWS * 6 / 4) {
        const float4 v = reinterpret_cast<const float4*>(pred)[(size_t)b * (ROWS * 6 / 4) + t];
        reinterpret_cast<float4*>(predS)[t] = v;
    }
    // block-level exclusive scan of counts (threads >= ROWS contribute 0)
    const int i = b * ROWS + t;
    const int c = (t < ROWS && i < N) ? counts[i] : 0;
    int incl = c;
    for (int o = 1; o < 64; o <<= 1) {
        int x = __shfl_up(incl, o, 64);
        if (lane >= o) incl += x;
    }
    if (lane == 63) waveTot[w] = incl;
    __syncthreads();
    int wbase = 0;
    for (int ww = 0; ww < w; ++ww) wbase += waveTot[ww];
    const int localStart = wbase + incl - c;
    if (t == ROWS - 1) sTotal = localStart + c;   // rows >= ROWS have c=0
    if (t < ROWS) bestLds[t] = ~0ULL;
    for (int j = 0; j < c; ++j) ownerMap[localStart + j] = (u8)t;
    __syncthreads();

    const int base = blockOffsets[b];
    const int blockTotal = sTotal;
    const float2* gxy = reinterpret_cast<const float2*>(gt);

    // barrier-free gather: 8 independent strided loads in flight per thread
    for (int tile = 0; tile < blockTotal; tile += TPB * 8) {
        int j[8]; float2 g[8]; bool valid[8];
#pragma unroll
        for (int u = 0; u < 8; ++u) {
            j[u] = tile + u * TPB + t;
            valid[u] = j[u] < blockTotal;
            if (valid[u]) g[u] = gxy[(size_t)(base + j[u]) * 3];
        }
#pragma unroll
        for (int u = 0; u < 8; ++u) {
            if (valid[u]) {
                const int owner = (int)ownerMap[j[u]];
                const float px = predS[owner * 6], py = predS[owner * 6 + 1];
                const float dx = px - g[u].x, dy = py - g[u].y;
                const float d2 = dx * dx + dy * dy;  // >=0: IEEE-monotone bits
                const u64 key = ((u64)__float_as_uint(d2) << 32)
                              | (unsigned int)(base + j[u]);
                if (key < bestLds[owner]) atomicMin(&bestLds[owner], key);
            }
        }
    }
    __syncthreads();

    float lp = 0.f, la = 0.f, lw = 0.f, ls = 0.f;
    if (t < ROWS && i < N && c > 0) {
        const u64 key = bestLds[t];
        const float d2 = __uint_as_float((unsigned int)(key >> 32));
        const int bj = (int)(key & 0xffffffffu);
        lp = 1.0f - expf(-d2 / 0.045f);  // max resp == exp(-min d2/(2 sigma^2))

        const float p2 = predS[t * 6 + 2], p3 = predS[t * 6 + 3];
        const float p4 = predS[t * 6 + 4], p5 = predS[t * 6 + 5];
        const float* ng = gt + (size_t)bj * 6;
        const float2 g23 = *reinterpret_cast<const float2*>(ng + 2);
        const float2 g45 = *reinterpret_cast<const float2*>(ng + 4);

        la = fabsf(p2 - g23.x) + fabsf(p3 - g23.y);
        const float d = p4 - g45.x;
        const float ad = fabsf(d);
        lw = (ad < 1.0f) ? 0.5f * d * d : ad - 0.5f;
        if (g45.y > 0.0f) {
            ls = fmaxf(p5, 0.0f) - p5 * g45.y + log1pf(expf(-fabsf(p5)));
        }
    }

    for (int o = 32; o > 0; o >>= 1) {
        lp += __shfl_down(lp, o, 64);
        la += __shfl_down(la, o, 64);
        lw += __shfl_down(lw, o, 64);
        ls += __shfl_down(ls, o, 64);
    }
    if (lane == 0) { red[w][0] = lp; red[w][1] = la; red[w][2] = lw; red[w][3] = ls; }
    __syncthreads();
    if (t == 0) {
        float s0 = 0, s1 = 0, s2 = 0, s3 = 0;
        for (int ww = 0; ww < TPB / 64; ++ww) {
            s0 += red[ww][0]; s1 += red[ww][1]; s2 += red[ww][2]; s3 += red[ww][3];
        }
        partials[b] = make_float4(s0, s1, s2, s3);  // distinct slot: no atomics
    }
}

// Reduce 2048 per-block partials (1024 threads x 2); f64 accumulation.
__global__ void finalize_kernel(const float4* __restrict__ partials,
                                float* __restrict__ out, int nb, int N) {
    const int t = threadIdx.x;
    const int lane = t & 63, w = t >> 6;
    double s0 = 0, s1 = 0, s2 = 0, s3 = 0;
    for (int q = t; q < nb; q += 1024) {
        const float4 v = partials[q];
        s0 += v.x; s1 += v.y; s2 += v.z; s3 += v.w;
    }
    for (int o = 32; o > 0; o >>= 1) {
        s0 += __shfl_down(s0, o, 64);
        s1 += __shfl_down(s1, o, 64);
        s2 += __shfl_down(s2, o, 64);
        s3 += __shfl_down(s3, o, 64);
    }
    __shared__ double red[16][4];
    if (lane == 0) { red[w][0] = s0; red[w][1] = s1; red[w][2] = s2; red[w][3] = s3; }
    __syncthreads();
    if (t == 0) {
        double t0 = 0, t1 = 0, t2 = 0, t3 = 0;
        for (int ww = 0; ww < 16; ++ww) {
            t0 += red[ww][0]; t1 += red[ww][1]; t2 += red[ww][2]; t3 += red[ww][3];
        }
        const double inv = 1.0 / (double)N;
        const float lp = (float)(t0 * inv);
        const float la = (float)(t1 * inv);
        const float lw = (float)(t2 * inv);
        const float ls = (float)(t3 * inv);
        out[0] = lp; out[1] = la; out[2] = lw; out[3] = ls;
        out[4] = lp + la + lw + 0.5f * ls;
    }
}

extern "C" void kernel_launch(void* const* d_in, const int* in_sizes, int n_in,
                              void* d_out, int out_size, void* d_ws, size_t ws_size,
                              hipStream_t stream) {
    const float* pred = (const float*)d_in[0];
    const float* gt = (const float*)d_in[1];
    const int* counts = (const int*)d_in[2];
    float* out = (float*)d_out;

    const int N = in_sizes[2];
    const int nb = (N + ROWS - 1) / ROWS;  // 2048

    int* blockSums = (int*)d_ws;
    int* blockOffsets = (int*)((char*)d_ws + 8192);
    float4* partials = (float4*)((char*)d_ws + 16384);

    block_sum_kernel<<<nb, 64, 0, stream>>>(counts, blockSums, N);
    scan_kernel<<<1, 1024, 0, stream>>>(blockSums, blockOffsets, nb);
    fused_kernel<<<nb, TPB, 0, stream>>>(pred, gt, counts, blockOffsets,
                                         partials, N);
    finalize_kernel<<<1, 1024, 0, stream>>>(partials, out, nb, N);
}

// Round 11
// 166.413 us; speedup vs baseline: 1.4320x; 1.0339x over previous
//
#include <hip/hip_runtime.h>
#include <math.h>
#include <float.h>

#define BS 256
#define MAXC 31
#define MAXGT (BS * MAXC)   // 7936 max gt rows per block
typedef unsigned long long u64;
typedef unsigned char u8;

// ws layout (nb = 1024):
//   [0, 4K)        int blockSums[nb]
//   [4K, 8K)       int blockOffsets[nb]
//   [8K, 24K)      float4 partials[nb]   (lp, la, lw, ls per block)

__global__ void block_sum_kernel(const int* __restrict__ counts,
                                 int* __restrict__ blockSums, int N) {
    int i = blockIdx.x * BS + threadIdx.x;
    int v = (i < N) ? counts[i] : 0;
    for (int o = 32; o > 0; o >>= 1) v += __shfl_down(v, o, 64);
    __shared__ int ws[BS / 64];
    int lane = threadIdx.x & 63, w = threadIdx.x >> 6;
    if (lane == 0) ws[w] = v;
    __syncthreads();
    if (threadIdx.x == 0) {
        int s = 0;
        for (int ww = 0; ww < BS / 64; ++ww) s += ws[ww];
        blockSums[blockIdx.x] = s;
    }
}

__global__ void scan_kernel(const int* __restrict__ blockSums,
                            int* __restrict__ blockOffsets, int nb) {
    __shared__ int tmp[1024];
    int t = threadIdx.x;
    int v = (t < nb) ? blockSums[t] : 0;
    tmp[t] = v;
    __syncthreads();
    for (int off = 1; off < 1024; off <<= 1) {
        int x = (t >= off) ? tmp[t - off] : 0;
        __syncthreads();
        tmp[t] += x;
        __syncthreads();
    }
    if (t < nb) blockOffsets[t] = tmp[t] - v;  // exclusive
}

// Block b owns pred rows [b*256, b*256+256) and their contiguous gt range.
// ownerMap[j] (u8: owner in [0,256)) gives the owning pred row for local gt
// row j. Read-before-atomic guard kills ~16-way same-address LDS atomic
// contention (stale reads only over-admit; final value still exact min).
__global__ void __launch_bounds__(BS)
fused_kernel(const float* __restrict__ pred, const float* __restrict__ gt,
             const int* __restrict__ counts, const int* __restrict__ blockOffsets,
             float4* __restrict__ partials, int N) {
    const int t = threadIdx.x;
    const int b = blockIdx.x;
    const int i = b * BS + t;
    const int lane = t & 63, w = t >> 6;

    __shared__ u8 ownerMap[MAXGT];      // 7936 B
    __shared__ float2 pxy[BS];          // 2048 B
    __shared__ u64 bestLds[BS];         // 2048 B
    __shared__ int waveTot[BS / 64];
    __shared__ int sTotal;
    __shared__ float red[BS / 64][4];

    const int c = (i < N) ? counts[i] : 0;
    int incl = c;
    for (int o = 1; o < 64; o <<= 1) {
        int x = __shfl_up(incl, o, 64);
        if (lane >= o) incl += x;
    }
    if (lane == 63) waveTot[w] = incl;
    __syncthreads();
    int wbase = 0;
    for (int ww = 0; ww < w; ++ww) wbase += waveTot[ww];
    const int localStart = wbase + incl - c;
    if (t == BS - 1) sTotal = localStart + c;
    bestLds[t] = ~0ULL;
    if (i < N) pxy[t] = reinterpret_cast<const float2*>(pred)[(size_t)i * 3];
    // fill owner map for this row's segment (independent byte writes)
    for (int j = 0; j < c; ++j) ownerMap[localStart + j] = (u8)t;
    __syncthreads();

    const int base = blockOffsets[b];
    const int blockTotal = sTotal;
    const float2* gxy = reinterpret_cast<const float2*>(gt);

    // tile loop, unrolled x4: 4 independent global loads + short LDS chains
    for (int tile = 0; tile < blockTotal; tile += BS * 4) {
        int j[4]; float2 g[4]; bool valid[4];
#pragma unroll
        for (int u = 0; u < 4; ++u) {
            j[u] = tile + u * BS + t;
            valid[u] = j[u] < blockTotal;
            if (valid[u]) g[u] = gxy[(size_t)(base + j[u]) * 3];
        }
#pragma unroll
        for (int u = 0; u < 4; ++u) {
            if (valid[u]) {
                const int owner = (int)ownerMap[j[u]];
                const float2 p = pxy[owner];
                const float dx = p.x - g[u].x, dy = p.y - g[u].y;
                const float d2 = dx * dx + dy * dy;  // >=0: IEEE-monotone bits
                const u64 key = ((u64)__float_as_uint(d2) << 32)
                              | (unsigned int)(base + j[u]);
                // guard: only contend when we might improve the min
                if (key < bestLds[owner]) atomicMin(&bestLds[owner], key);
            }
        }
    }
    __syncthreads();

    float lp = 0.f, la = 0.f, lw = 0.f, ls = 0.f;
    if (i < N && c > 0) {
        const u64 key = bestLds[t];
        const float d2 = __uint_as_float((unsigned int)(key >> 32));
        const int bj = (int)(key & 0xffffffffu);
        lp = 1.0f - expf(-d2 / 0.045f);  // max resp == exp(-min d2/(2 sigma^2))

        const float* p = pred + (size_t)i * 6;
        const float2 p23 = *reinterpret_cast<const float2*>(p + 2);
        const float2 p45 = *reinterpret_cast<const float2*>(p + 4);
        const float* ng = gt + (size_t)bj * 6;
        const float2 g23 = *reinterpret_cast<const float2*>(ng + 2);
        const float2 g45 = *reinterpret_cast<const float2*>(ng + 4);

        la = fabsf(p23.x - g23.x) + fabsf(p23.y - g23.y);
        const float d = p45.x - g45.x;
        const float ad = fabsf(d);
        lw = (ad < 1.0f) ? 0.5f * d * d : ad - 0.5f;
        const float x = p45.y;
        if (g45.y > 0.0f) {
            ls = fmaxf(x, 0.0f) - x * g45.y + log1pf(expf(-fabsf(x)));
        }
    }

    for (int o = 32; o > 0; o >>= 1) {
        lp += __shfl_down(lp, o, 64);
        la += __shfl_down(la, o, 64);
        lw += __shfl_down(lw, o, 64);
        ls += __shfl_down(ls, o, 64);
    }
    if (lane == 0) { red[w][0] = lp; red[w][1] = la; red[w][2] = lw; red[w][3] = ls; }
    __syncthreads();
    if (t == 0) {
        float s0 = 0, s1 = 0, s2 = 0, s3 = 0;
        for (int ww = 0; ww < BS / 64; ++ww) {
            s0 += red[ww][0]; s1 += red[ww][1]; s2 += red[ww][2]; s3 += red[ww][3];
        }
        partials[b] = make_float4(s0, s1, s2, s3);  // distinct slot: no atomics
    }
}

// Reduce 1024 per-block partials in one block; f64 accumulation.
__global__ void finalize_kernel(const float4* __restrict__ partials,
                                float* __restrict__ out, int nb, int N) {
    const int t = threadIdx.x;
    const int lane = t & 63, w = t >> 6;
    double s0 = 0, s1 = 0, s2 = 0, s3 = 0;
    if (t < nb) {
        const float4 v = partials[t];
        s0 = v.x; s1 = v.y; s2 = v.z; s3 = v.w;
    }
    for (int o = 32; o > 0; o >>= 1) {
        s0 += __shfl_down(s0, o, 64);
        s1 += __shfl_down(s1, o, 64);
        s2 += __shfl_down(s2, o, 64);
        s3 += __shfl_down(s3, o, 64);
    }
    __shared__ double red[16][4];
    if (lane == 0) { red[w][0] = s0; red[w][1] = s1; red[w][2] = s2; red[w][3] = s3; }
    __syncthreads();
    if (t == 0) {
        double t0 = 0, t1 = 0, t2 = 0, t3 = 0;
        for (int ww = 0; ww < blockDim.x / 64; ++ww) {
            t0 += red[ww][0]; t1 += red[ww][1]; t2 += red[ww][2]; t3 += red[ww][3];
        }
        const double inv = 1.0 / (double)N;
        const float lp = (float)(t0 * inv);
        const float la = (float)(t1 * inv);
        const float lw = (float)(t2 * inv);
        const float ls = (float)(t3 * inv);
        out[0] = lp; out[1] = la; out[2] = lw; out[3] = ls;
        out[4] = lp + la + lw + 0.5f * ls;
    }
}

extern "C" void kernel_launch(void* const* d_in, const int* in_sizes, int n_in,
                              void* d_out, int out_size, void* d_ws, size_t ws_size,
                              hipStream_t stream) {
    const float* pred = (const float*)d_in[0];
    const float* gt = (const float*)d_in[1];
    const int* counts = (const int*)d_in[2];
    float* out = (float*)d_out;

    const int N = in_sizes[2];
    const int numBlocks = (N + BS - 1) / BS;  // 1024

    int* blockSums = (int*)d_ws;
    int* blockOffsets = (int*)((char*)d_ws + 4096);
    float4* partials = (float4*)((char*)d_ws + 8192);

    block_sum_kernel<<<numBlocks, BS, 0, stream>>>(counts, blockSums, N);
    scan_kernel<<<1, 1024, 0, stream>>>(blockSums, blockOffsets, numBlocks);
    fused_kernel<<<numBlocks, BS, 0, stream>>>(pred, gt, counts, blockOffsets,
                                               partials, N);
    finalize_kernel<<<1, 1024, 0, stream>>>(partials, out, numBlocks, N);
}